// Round 5
// baseline (54.458 us; speedup 1.0000x reference)
//
#include <hip/hip_runtime.h>
#include <math.h>

#define B 128
#define E 6
#define IN_DIM 1664
#define H_DIM 512
#define OUT_DIM 618
#define ZD 32
#define K2 (H_DIM + ZD)   // 544
#define KB1 52            // k32-blocks in L1 (1664/32)
#define KB23 17           // k32-blocks in L2/L3 (544/32)
#define NPAD3 640         // L3 col space padded (frags + partials)

typedef __attribute__((ext_vector_type(8))) short short8;
typedef __attribute__((ext_vector_type(4))) float f32x4;

union U128 { uint4 u4; short8 s8; ushort us[8]; };

__device__ __forceinline__ ushort f2bf(float f) {   // fp32 -> bf16 RNE
    uint u = __float_as_uint(f);
    u += 0x7fffu + ((u >> 16) & 1u);
    return (ushort)(u >> 16);
}

// ---------------------------------------------------------------------------
// prep_a1: A1 frags [E][KB1][8][64][8] bf16, lane l of frag (e,kb,m):
//   row = 16m+(l&15), k = 32kb+(l>>4)*8+j, value = coef[row,e]*x[row,k]
// (validated on HW in r3: absmax 0.125)
// ---------------------------------------------------------------------------
__global__ __launch_bounds__(256) void prep_a1(
    const float* __restrict__ x, const float* __restrict__ coef,
    ushort* __restrict__ a1)
{
    const int u = blockIdx.x * 256 + threadIdx.x;
    if (u >= E * KB1 * 8 * 64) return;
    const int l = u & 63;
    int t = u >> 6;
    const int m = t & 7; t >>= 3;
    const int kb = t % KB1; const int e = t / KB1;
    const int row = m * 16 + (l & 15);
    const int k0  = kb * 32 + ((l >> 4) << 3);
    const float c = coef[row * E + e];
    const float4 v0 = *reinterpret_cast<const float4*>(x + (size_t)row * IN_DIM + k0);
    const float4 v1 = *reinterpret_cast<const float4*>(x + (size_t)row * IN_DIM + k0 + 4);
    U128 r;
    r.us[0] = f2bf(v0.x * c); r.us[1] = f2bf(v0.y * c);
    r.us[2] = f2bf(v0.z * c); r.us[3] = f2bf(v0.w * c);
    r.us[4] = f2bf(v1.x * c); r.us[5] = f2bf(v1.y * c);
    r.us[6] = f2bf(v1.z * c); r.us[7] = f2bf(v1.w * c);
    *reinterpret_cast<uint4*>(a1 + (size_t)u * 8) = r.u4;
}

// ---------------------------------------------------------------------------
// Fused-conversion MFMA gemm. Block 256 = 4 waves; block tile 128 rows x
// 32 cols; wave tile 32x32. Per (e,kb): W fp32 tile (32k x 32n) loaded
// cooperatively (4 dword/thread along k, 2x128B per wave per instr),
// converted in-reg to bf16, ds_write 8B into frag layout; waves ds_read_b128
// their 2 B-frags + load 2 precomputed A-frags; 4 MFMA. 1-deep register
// prefetch of next (A,B) across the barrier pair. Split-K partials.
//   KBTOT: k32-blocks total; KPB: k-blocks per split;
//   NW: real W col count & row stride; NP: padded frag/partial col space.
// ---------------------------------------------------------------------------
template<int KBTOT, int KPB, int NW, int NP>
__global__ __launch_bounds__(256) void moe_mfma_gemm(
    const uint4* __restrict__ afrag,   // [E][KBTOT][8][64] 16B frags
    const float* __restrict__ w,       // [E][KBTOT*32][NW] fp32
    float* __restrict__ part)          // [S][B][NP]
{
    const int l   = threadIdx.x & 63;
    const int wv  = threadIdx.x >> 6;
    const int n0  = blockIdx.x * 32;
    const int kb0 = blockIdx.y * KPB;

    // B-staging mapping: thread t stages (k = tkq*4..tkq*4+3, col n0+tn)
    const int tn   = threadIdx.x & 31;
    const int tkq  = threadIdx.x >> 5;               // 0..7
    const int lp   = ((tkq >> 1) << 4) | (tn & 15);  // frag lane
    const int fI   = tn >> 4;                        // frag index 0/1
    const int j0   = (tkq & 1) << 2;                 // j offset 0/4
    const int colW = n0 + tn;

    __shared__ ushort bs[2][64][8];                  // [frag][lane][j] 2KB

    f32x4 acc00 = {0.f,0.f,0.f,0.f}, acc01 = {0.f,0.f,0.f,0.f};
    f32x4 acc10 = {0.f,0.f,0.f,0.f}, acc11 = {0.f,0.f,0.f,0.f};

    auto load_B = [&](int e, int kb, float* r) {
        const float* src = w + ((size_t)e * (KBTOT * 32) + kb * 32 + tkq * 4) * NW + colW;
        #pragma unroll
        for (int j = 0; j < 4; ++j)
            r[j] = (colW < NW) ? src[(size_t)j * NW] : 0.f;  // zero-pad L3 cols
    };
    auto load_A = [&](int e, int kb, U128& x0, U128& x1) {
        const size_t ab = ((size_t)e * KBTOT + kb) * 8;
        x0.u4 = afrag[(ab + 2 * wv    ) * 64 + l];
        x1.u4 = afrag[(ab + 2 * wv + 1) * 64 + l];
    };

    float wr[4];
    U128 a0, a1;
    load_B(0, kb0, wr);
    load_A(0, kb0, a0, a1);

    #pragma unroll
    for (int kbi = 0; kbi < KPB; ++kbi) {
        const int kb = kb0 + kbi;
        #pragma unroll
        for (int e = 0; e < E; ++e) {
            __syncthreads();                         // prev LDS reads done
            {   // stage current B tile (cvt once per weight element)
                uint2 pk;
                pk.x = (uint)f2bf(wr[0]) | ((uint)f2bf(wr[1]) << 16);
                pk.y = (uint)f2bf(wr[2]) | ((uint)f2bf(wr[3]) << 16);
                *reinterpret_cast<uint2*>(&bs[fI][lp][j0]) = pk;
            }
            // prefetch next (e,kb)
            float wrn[4] = {0.f, 0.f, 0.f, 0.f};
            U128 a0n{}, a1n{};
            if (!(e == E - 1 && kbi == KPB - 1)) {
                const int en = (e == E - 1) ? 0 : e + 1;
                const int kn = (e == E - 1) ? kb + 1 : kb;
                load_B(en, kn, wrn);
                load_A(en, kn, a0n, a1n);
            }
            __syncthreads();                         // staged tile visible

            U128 b0, b1;
            b0.u4 = *reinterpret_cast<const uint4*>(&bs[0][l][0]);
            b1.u4 = *reinterpret_cast<const uint4*>(&bs[1][l][0]);
            acc00 = __builtin_amdgcn_mfma_f32_16x16x32_bf16(a0.s8, b0.s8, acc00, 0, 0, 0);
            acc01 = __builtin_amdgcn_mfma_f32_16x16x32_bf16(a0.s8, b1.s8, acc01, 0, 0, 0);
            acc10 = __builtin_amdgcn_mfma_f32_16x16x32_bf16(a1.s8, b0.s8, acc10, 0, 0, 0);
            acc11 = __builtin_amdgcn_mfma_f32_16x16x32_bf16(a1.s8, b1.s8, acc11, 0, 0, 0);

            wr[0] = wrn[0]; wr[1] = wrn[1]; wr[2] = wrn[2]; wr[3] = wrn[3];
            a0 = a0n; a1 = a1n;
        }
    }

    // C/D layout (HW-validated r3): col = l&15, row = (l>>4)*4 + r
    float* pb = part + (size_t)blockIdx.y * B * NP;
    const int colB = n0 + (l & 15);
    const int rsub = (l >> 4) << 2;
    #pragma unroll
    for (int mi = 0; mi < 2; ++mi) {
        const int row = wv * 32 + mi * 16 + rsub;
        const f32x4 c0 = mi ? acc10 : acc00;
        const f32x4 c1 = mi ? acc11 : acc01;
        #pragma unroll
        for (int r = 0; r < 4; ++r) {
            pb[(size_t)(row + r) * NP + colB]      = c0[r];
            pb[(size_t)(row + r) * NP + colB + 16] = c1[r];
        }
    }
}

// ---------------------------------------------------------------------------
// finalize (L1/L2): reduce split-K partials + blended bias + ELU, emit next
// layer's A-frags (coef-folded bf16, incl. z cols). Thread owns (b, 4 k's).
// ---------------------------------------------------------------------------
template<int S>
__global__ __launch_bounds__(256) void moe_finalize_mid(
    const float* __restrict__ part,     // [S][B][H_DIM]
    const float* __restrict__ coef,     // [B][E]
    const float* __restrict__ bias,     // [E][H_DIM]
    const float* __restrict__ z,        // [B][ZD]
    ushort* __restrict__ anext)         // [E][KB23][8][64][8]
{
    const int idx = blockIdx.x * 256 + threadIdx.x;   // B*K2/4 = 17408
    if (idx >= B * (K2 / 4)) return;
    const int b  = idx / (K2 / 4);
    const int o4 = (idx % (K2 / 4)) * 4;

    float vx, vy, vz2, vw;
    if (o4 < H_DIM) {
        float s0 = 0.f, s1 = 0.f, s2 = 0.f, s3 = 0.f;
        #pragma unroll 4
        for (int s = 0; s < S; ++s) {
            const float4 p = *reinterpret_cast<const float4*>(
                part + ((size_t)s * B + b) * H_DIM + o4);
            s0 += p.x; s1 += p.y; s2 += p.z; s3 += p.w;
        }
        #pragma unroll
        for (int e = 0; e < E; ++e) {
            const float c = coef[b * E + e];
            const float4 bb = *reinterpret_cast<const float4*>(
                bias + (size_t)e * H_DIM + o4);
            s0 = fmaf(c, bb.x, s0); s1 = fmaf(c, bb.y, s1);
            s2 = fmaf(c, bb.z, s2); s3 = fmaf(c, bb.w, s3);
        }
        vx  = s0 < 0.f ? expm1f(s0) : s0;
        vy  = s1 < 0.f ? expm1f(s1) : s1;
        vz2 = s2 < 0.f ? expm1f(s2) : s2;
        vw  = s3 < 0.f ? expm1f(s3) : s3;
    } else {
        const float4 zv = *reinterpret_cast<const float4*>(z + b * ZD + (o4 - H_DIM));
        vx = zv.x; vy = zv.y; vz2 = zv.z; vw = zv.w;
    }

    const int kb = o4 >> 5;
    const int l  = (((o4 >> 3) & 3) << 4) | (b & 15);
    const int j0 = o4 & 7;               // 0 or 4
    const int m  = b >> 4;
    #pragma unroll
    for (int e = 0; e < E; ++e) {
        const float c = coef[b * E + e];
        uint2 pk;
        pk.x = (uint)f2bf(vx * c)  | ((uint)f2bf(vy * c) << 16);
        pk.y = (uint)f2bf(vz2 * c) | ((uint)f2bf(vw * c) << 16);
        *reinterpret_cast<uint2*>(
            anext + ((((size_t)e * KB23 + kb) * 8 + m) * 64 + l) * 8 + j0) = pk;
    }
}

// finalize (L3): partial reduce (padded stride) + blended bias -> d_out.
template<int S>
__global__ __launch_bounds__(256) void moe_finalize_last(
    const float* __restrict__ part,     // [S][B][NPAD3]
    const float* __restrict__ coef,
    const float* __restrict__ bias,     // [E][OUT_DIM]
    float* __restrict__ out)            // [B][OUT_DIM]
{
    const int idx = blockIdx.x * 256 + threadIdx.x;
    if (idx >= B * OUT_DIM) return;
    const int b = idx / OUT_DIM;
    const int o = idx - b * OUT_DIM;
    float v = 0.f;
    #pragma unroll 4
    for (int s = 0; s < S; ++s) v += part[((size_t)s * B + b) * NPAD3 + o];
    #pragma unroll
    for (int e = 0; e < E; ++e)
        v = fmaf(coef[b * E + e], bias[(size_t)e * OUT_DIM + o], v);
    out[idx] = v;
}

extern "C" void kernel_launch(void* const* d_in, const int* in_sizes, int n_in,
                              void* d_out, int out_size, void* d_ws, size_t ws_size,
                              hipStream_t stream)
{
    const float* p_prev = (const float*)d_in[0];
    const float* coef   = (const float*)d_in[1];
    const float* z      = (const float*)d_in[2];
    const float* w1     = (const float*)d_in[3];
    const float* b1     = (const float*)d_in[4];
    const float* w2     = (const float*)d_in[5];
    const float* b2     = (const float*)d_in[6];
    const float* w3     = (const float*)d_in[7];
    const float* b3     = (const float*)d_in[8];
    float* out = (float*)d_out;

    // ws layout (bytes), total ~11 MB
    char* p = (char*)d_ws;
    ushort* a1 = (ushort*)p; p += (size_t)E * KB1  * 8 * 64 * 16;  // 2,555,904
    ushort* a2 = (ushort*)p; p += (size_t)E * KB23 * 8 * 64 * 16;  //   835,584
    ushort* a3 = (ushort*)p; p += (size_t)E * KB23 * 8 * 64 * 16;  //   835,584
    float* part = (float*)p;  // max(26*128*512, 17*128*640)*4 = 6,815,744

    // 1) A1 frags (tiny)
    prep_a1<<<624, 256, 0, stream>>>(p_prev, coef, a1);

    // 2) L1: K=1664 (52 kb), kc=64 -> 26 splits, N=512
    moe_mfma_gemm<KB1, 2, H_DIM, H_DIM><<<dim3(16, 26), 256, 0, stream>>>(
        (const uint4*)a1, w1, part);
    moe_finalize_mid<26><<<68, 256, 0, stream>>>(part, coef, b1, z, a2);

    // 3) L2: K=544 (17 kb), kc=32 -> 17 splits, N=512
    moe_mfma_gemm<KB23, 1, H_DIM, H_DIM><<<dim3(16, 17), 256, 0, stream>>>(
        (const uint4*)a2, w2, part);
    moe_finalize_mid<17><<<68, 256, 0, stream>>>(part, coef, b2, z, a3);

    // 4) L3: K=544, N=618 (padded to 640 in frag/partial space)
    moe_mfma_gemm<KB23, 1, OUT_DIM, NPAD3><<<dim3(20, 17), 256, 0, stream>>>(
        (const uint4*)a3, w3, part);
    moe_finalize_last<17><<<(B * OUT_DIM + 255) / 256, 256, 0, stream>>>(
        part, coef, b3, out);
}